// Round 1
// baseline (564.396 us; speedup 1.0000x reference)
//
#include <hip/hip_runtime.h>
#include <stdint.h>

#define N_NODES 10000
#define N_EDGES 160000
#define N_REL   4
#define N_GRAPHS 256
#define NBUCKET (N_NODES * N_REL)   // 40000 (dst,rel) buckets

typedef __attribute__((ext_vector_type(8))) short short8;
typedef __attribute__((ext_vector_type(4))) float float4v;

// ---------- helpers ----------
__device__ __forceinline__ unsigned short f2bf(float f) {
  unsigned int u = __float_as_uint(f);
  u = u + 0x7FFFu + ((u >> 16) & 1u);   // round-to-nearest-even
  return (unsigned short)(u >> 16);
}
__device__ __forceinline__ float bf2f(unsigned short b) {
  return __uint_as_float(((unsigned int)b) << 16);
}

__device__ __forceinline__ void g2lds16(const void* g, void* l) {
  // async global->LDS, 16B per lane; LDS dest = wave-uniform base + lane*16
  __builtin_amdgcn_global_load_lds(
      (const __attribute__((address_space(1))) void*)g,
      (__attribute__((address_space(3))) void*)l, 16, 0, 0);
}

__device__ __forceinline__ int lower_bound_i(const int* a, int n, int key) {
  int lo = 0, hi = n;
  while (lo < hi) { int mid = (lo + hi) >> 1; if (a[mid] < key) lo = mid + 1; else hi = mid; }
  return lo;
}

// ---------- CSR build ----------
__global__ void count_edges_k(const int* __restrict__ ei, const int* __restrict__ et,
                              int* __restrict__ cnt, int E) {
  int e = blockIdx.x * 256 + threadIdx.x;
  if (e < E) atomicAdd(&cnt[ei[E + e] * N_REL + et[e]], 1);
}

__global__ void scan_block_k(const int* __restrict__ cnt, int* __restrict__ eexcl,
                             int* __restrict__ btot, int n) {
  int i = blockIdx.x * 256 + threadIdx.x;
  int v = (i < n) ? cnt[i] : 0;
  int lane = threadIdx.x & 63, wv = threadIdx.x >> 6;
  int s = v;
  #pragma unroll
  for (int off = 1; off < 64; off <<= 1) {
    int t = __shfl_up(s, off, 64);
    if (lane >= off) s += t;
  }
  __shared__ int wt[4];
  if (lane == 63) wt[wv] = s;
  __syncthreads();
  int wadd = 0;
  for (int w = 0; w < wv; ++w) wadd += wt[w];
  int incl = s + wadd;
  if (i < n) eexcl[i] = incl - v;
  if (threadIdx.x == 255) btot[blockIdx.x] = incl;
}

__global__ void scan_final_k(const int* __restrict__ cnt, const int* __restrict__ eexcl,
                             const int* __restrict__ btot, int* __restrict__ offs,
                             int* __restrict__ cursor, float* __restrict__ inv, int n) {
  __shared__ int wred[4];
  __shared__ int sboff;
  int t = threadIdx.x;
  int part = (t < (int)blockIdx.x) ? btot[t] : 0;   // gridDim <= 256
  #pragma unroll
  for (int off = 32; off > 0; off >>= 1) part += __shfl_down(part, off, 64);
  if ((t & 63) == 0) wred[t >> 6] = part;
  __syncthreads();
  if (t == 0) sboff = wred[0] + wred[1] + wred[2] + wred[3];
  __syncthreads();
  int i = blockIdx.x * 256 + t;
  if (i < n) {
    int o = sboff + eexcl[i];
    offs[i] = o;
    cursor[i] = o;
    int c = cnt[i];
    inv[i] = 1.0f / (float)(c > 1 ? c : 1);
  }
}

__global__ void fill_csr_k(const int* __restrict__ ei, const int* __restrict__ et,
                           int* __restrict__ cursor, int* __restrict__ elist, int E) {
  int e = blockIdx.x * 256 + threadIdx.x;
  if (e >= E) return;
  int dst = ei[E + e], src = ei[e], r = et[e];
  int pos = atomicAdd(&cursor[dst * N_REL + r], 1);
  elist[pos] = src;
}

// ---------- Wcat build: [F][K] bf16, K = 5*Din, rows 0..4Din-1 from W, rest from root ----------
__global__ void wcat_transpose_k(const float* __restrict__ W, const float* __restrict__ root,
                                 unsigned short* __restrict__ out, int Din4, int F, int K) {
  __shared__ float tile[32][33];
  int kb = blockIdx.x * 32, fb = blockIdx.y * 32;
  for (int i = threadIdx.y; i < 32; i += 8) {
    int k = kb + i, f = fb + threadIdx.x;
    float v = 0.0f;
    if (k < K && f < F) v = (k < Din4) ? W[(size_t)k * F + f] : root[(size_t)(k - Din4) * F + f];
    tile[i][threadIdx.x] = v;
  }
  __syncthreads();
  for (int i = threadIdx.y; i < 32; i += 8) {
    int f = fb + i, k = kb + threadIdx.x;
    if (f < F && k < K) out[(size_t)f * K + k] = f2bf(tile[threadIdx.x][i]);
  }
}

// ---------- layer-1 aggregation (Din=64, fp32 x): one wave per (node, rel) ----------
__global__ void aggregate64_k(const float* __restrict__ x, const int* __restrict__ offs,
                              const int* __restrict__ cnt, const float* __restrict__ inv,
                              const int* __restrict__ elist, unsigned short* __restrict__ Xcat) {
  const int n = blockIdx.x;
  const int wv = threadIdx.x >> 6;    // relation
  const int col = threadIdx.x & 63;
  const int b = n * N_REL + wv;
  const int start = offs[b], c = cnt[b];
  const float sc = inv[b];
  float acc = 0.0f;
  for (int j = 0; j < c; ++j) {
    int s = elist[start + j];          // wave-uniform scalar load
    acc += x[(size_t)s * 64 + col];
  }
  Xcat[(size_t)n * 320 + wv * 64 + col] = f2bf(acc * sc);
  if (wv == 0)
    Xcat[(size_t)n * 320 + 256 + col] = f2bf(x[(size_t)n * 64 + col]);
}

// ---------- aggregation (Din=1024, bf16 h), column-sliced for L2 residency ----------
// R5 rewrite: latency-bound, not BW-bound (gather traffic ~328MB is mostly
// L2-resident => ~10us at L2 BW, yet kernel was ~100us). Two fixes:
//  (a) 4-wave (256-thread) blocks: 4 nodes x SAME 256-col chunk per block,
//      lifting the 1-wave-workgroup occupancy cap (16 wg/CU) to 32 waves/CU.
//  (b) 4-wide unrolled gather loop: 4 independent 8B loads in flight per wave
//      instead of 1 (ds_read sid -> load -> acc serial chain removed; edge ids
//      now read as wave-uniform broadcast loads, no LDS staging, no barriers).
// XCD slice pinning preserved: chunk = (bid&7)>>1, so chunk-c blocks still
// land on XCDs {2c,2c+1} (heuristic XCD = bid%8); each 10000x256x2B = 5.1MB
// slice stays resident in that L2 pair. Per-relation summation order is
// unchanged (ascending j, single accumulator) => bit-identical output.
__global__ __launch_bounds__(256) void aggregate_bf16_k(
    const unsigned short* __restrict__ h,
    const int* __restrict__ offs, const int* __restrict__ cnt,
    const float* __restrict__ inv, const int* __restrict__ elist,
    unsigned short* __restrict__ Xcat) {
  const int bid = blockIdx.x;
  const int chunk = (bid & 7) >> 1;
  const int wv = threadIdx.x >> 6;
  const int lane = threadIdx.x & 63;
  // bijective (node, chunk) mapping: n bit2 <- bid bit0, n bits[1:0] <- wave
  const int n = ((bid >> 3) << 3) | ((bid & 1) << 2) | wv;
  const int col = chunk * 256 + (lane << 2);    // 4 bf16 cols per lane (8B)
  const int Din = 1024, K5 = 5120;
  const int b0 = n * N_REL;

  #pragma unroll
  for (int r = 0; r < N_REL; ++r) {
    const int sr = offs[b0 + r];
    const int c = cnt[b0 + r];
    float a0 = 0.f, a1 = 0.f, a2 = 0.f, a3 = 0.f;
    int j = 0;
    for (; j + 4 <= c; j += 4) {
      const int s0 = elist[sr + j + 0];
      const int s1 = elist[sr + j + 1];
      const int s2 = elist[sr + j + 2];
      const int s3 = elist[sr + j + 3];
      ushort4 v0 = *(const ushort4*)(h + (size_t)s0 * Din + col);
      ushort4 v1 = *(const ushort4*)(h + (size_t)s1 * Din + col);
      ushort4 v2 = *(const ushort4*)(h + (size_t)s2 * Din + col);
      ushort4 v3 = *(const ushort4*)(h + (size_t)s3 * Din + col);
      a0 += bf2f(v0.x); a1 += bf2f(v0.y); a2 += bf2f(v0.z); a3 += bf2f(v0.w);
      a0 += bf2f(v1.x); a1 += bf2f(v1.y); a2 += bf2f(v1.z); a3 += bf2f(v1.w);
      a0 += bf2f(v2.x); a1 += bf2f(v2.y); a2 += bf2f(v2.z); a3 += bf2f(v2.w);
      a0 += bf2f(v3.x); a1 += bf2f(v3.y); a2 += bf2f(v3.z); a3 += bf2f(v3.w);
    }
    for (; j < c; ++j) {
      const int s = elist[sr + j];
      ushort4 v = *(const ushort4*)(h + (size_t)s * Din + col);
      a0 += bf2f(v.x); a1 += bf2f(v.y); a2 += bf2f(v.z); a3 += bf2f(v.w);
    }
    const float sc = inv[b0 + r];
    ushort4 o;
    o.x = f2bf(a0 * sc); o.y = f2bf(a1 * sc);
    o.z = f2bf(a2 * sc); o.w = f2bf(a3 * sc);
    *(ushort4*)&Xcat[(size_t)n * K5 + r * Din + col] = o;
  }
  // root block: copy h[n] bits directly
  *(ushort4*)&Xcat[(size_t)n * K5 + 4 * Din + col] =
      *(const ushort4*)(h + (size_t)n * Din + col);
}

// ---------- GEMM: C[M,F](bf16) = relu(A[M,K](bf16) @ Bt[F,K]^T(bf16) + bias) ----------
// BK=64, XOR-swizzled LDS (conflict-free, verified R4: SQ_LDS_BANK_CONFLICT=0).
// 1D grid = NX*80 blocks, XCD-banded mapping: xcd = bid%8 owns 10 contiguous
// row-strips x all NX columns, so each A-strip is fetched once per XCD and
// reused NX times from its L2 (A was being refetched ~4x across XCDs in R4:
// FETCH 408 MB vs 133 MB ideal).
__global__ __launch_bounds__(256) void gemm_bt_bias_relu_k(
    const short* __restrict__ A, const short* __restrict__ Bt,
    const float* __restrict__ bias, unsigned short* __restrict__ C,
    int M, int Ndim, int K, int NX) {
  __shared__ short As[128 * 64];   // 16 KB
  __shared__ short Bs[128 * 64];   // 16 KB

  const int bid = blockIdx.x;
  const int xcd = bid & 7;
  const int local = bid >> 3;              // [0, NX*10)
  const int t = xcd * (NX * 10) + local;   // contiguous tile band per XCD
  const int tileM = t / NX;                // [0, 80)
  const int tileN = t - tileM * NX;
  const int mBase = tileM * 128;
  const int nBase = tileN * 128;

  const int tid = threadIdx.x;
  const int wave = tid >> 6;
  const int lane = tid & 63;
  const int half = lane >> 4;     // k-quad 0..3
  const int lrow = lane & 15;
  const int wm = (wave >> 1) * 64;
  const int wn = (wave & 1) * 64;
  const int srow = lane >> 3;               // staging: row within 8-row group
  const int schunk = (lane & 7) ^ srow;     // swizzle: global chunk for this slot

  float4v acc[4][4] = {};

  for (int k0 = 0; k0 < K; k0 += 64) {
    #pragma unroll
    for (int p = 0; p < 4; ++p) {
      int rb = wave * 32 + p * 8;
      int r = rb + srow;
      int gr = mBase + r; if (gr > M - 1) gr = M - 1;
      g2lds16(A + (size_t)gr * K + k0 + schunk * 8, &As[rb * 64]);
      int gn = nBase + r; if (gn > Ndim - 1) gn = Ndim - 1;
      g2lds16(Bt + (size_t)gn * K + k0 + schunk * 8, &Bs[rb * 64]);
    }
    __syncthreads();

    #pragma unroll
    for (int kk = 0; kk < 2; ++kk) {
      short8 a[4], b[4];
      #pragma unroll
      for (int i = 0; i < 4; ++i) {
        int r = wm + i * 16 + lrow;
        int q = (kk * 4 + half) ^ (r & 7);
        a[i] = *(const short8*)&As[r * 64 + q * 8];
      }
      #pragma unroll
      for (int j = 0; j < 4; ++j) {
        int r = wn + j * 16 + lrow;
        int q = (kk * 4 + half) ^ (r & 7);
        b[j] = *(const short8*)&Bs[r * 64 + q * 8];
      }
      #pragma unroll
      for (int i = 0; i < 4; ++i)
        #pragma unroll
        for (int j = 0; j < 4; ++j)
          acc[i][j] = __builtin_amdgcn_mfma_f32_16x16x32_bf16(a[i], b[j], acc[i][j], 0, 0, 0);
    }
    __syncthreads();
  }

  #pragma unroll
  for (int i = 0; i < 4; ++i) {
    int row0 = mBase + wm + i * 16 + half * 4;
    #pragma unroll
    for (int j = 0; j < 4; ++j) {
      int col = nBase + wn + j * 16 + lrow;
      if (col < Ndim) {
        float bv = bias[col];
        #pragma unroll
        for (int r = 0; r < 4; ++r) {
          int rr = row0 + r;
          if (rr < M) C[(size_t)rr * Ndim + col] = f2bf(fmaxf(acc[i][j][r] + bv, 0.0f));
        }
      }
    }
  }
}

// ---------- fused pool + head MLP: one block per graph (bf16 h) ----------
__global__ __launch_bounds__(256) void pool_mlp_k(
    const unsigned short* __restrict__ h, const int* __restrict__ batch,
    const float* __restrict__ fw1, const float* __restrict__ fb1,
    const float* __restrict__ fw2, const float* __restrict__ fb2,
    float* __restrict__ out, int N, int F) {
  __shared__ float gsh[712];
  __shared__ float part[4][64];

  const int gid = blockIdx.x;
  const int tid = threadIdx.x;
  const int lo = lower_bound_i(batch, N, gid);
  const int hi = lower_bound_i(batch, N, gid + 1);
  const float scale = (hi > lo) ? 1.0f / (float)(hi - lo) : 0.0f;
  const int C4 = F >> 2;  // 178

  // stage 1: pooled mean into LDS
  if (tid < C4) {
    float a0 = 0.f, a1 = 0.f, a2 = 0.f, a3 = 0.f;
    for (int n = lo; n < hi; ++n) {
      ushort4 v = *(const ushort4*)(h + (size_t)n * F + tid * 4);
      a0 += bf2f(v.x); a1 += bf2f(v.y); a2 += bf2f(v.z); a3 += bf2f(v.w);
    }
    gsh[tid * 4 + 0] = a0 * scale;
    gsh[tid * 4 + 1] = a1 * scale;
    gsh[tid * 4 + 2] = a2 * scale;
    gsh[tid * 4 + 3] = a3 * scale;
  }
  __syncthreads();

  // stage 2: hidden-layer partial dot; f = lane, chunk = wave
  const int f = tid & 63;
  const int wv = tid >> 6;
  const int d0 = wv * 178;
  const int d1 = min(d0 + 178, F);
  float a = 0.0f;
  int d = d0;
  for (; d + 3 < d1; d += 4) {
    float g0 = gsh[d], g1 = gsh[d + 1], g2 = gsh[d + 2], g3 = gsh[d + 3];
    a += g0 * fw1[(size_t)d * 64 + f]
       + g1 * fw1[(size_t)(d + 1) * 64 + f]
       + g2 * fw1[(size_t)(d + 2) * 64 + f]
       + g3 * fw1[(size_t)(d + 3) * 64 + f];
  }
  for (; d < d1; ++d) a += gsh[d] * fw1[(size_t)d * 64 + f];
  part[wv][f] = a;
  __syncthreads();

  // stage 3: wave 0 reduces and finishes
  if (tid < 64) {
    float hsum = part[0][tid] + part[1][tid] + part[2][tid] + part[3][tid] + fb1[tid];
    hsum = fmaxf(hsum, 0.0f);
    float p = hsum * fw2[tid];
    #pragma unroll
    for (int off = 32; off > 0; off >>= 1) p += __shfl_down(p, off, 64);
    if (tid == 0) out[gid] = p + fb2[0];
  }
}

// ---------- launch ----------
extern "C" void kernel_launch(void* const* d_in, const int* in_sizes, int n_in,
                              void* d_out, int out_size, void* d_ws, size_t ws_size,
                              hipStream_t stream) {
  (void)in_sizes; (void)n_in; (void)out_size;
  const float* x    = (const float*)d_in[0];
  const int*  ei    = (const int*)d_in[1];
  const int*  et    = (const int*)d_in[2];
  const int*  batch = (const int*)d_in[3];
  const float* W1 = (const float*)d_in[4],  *root1 = (const float*)d_in[5],  *b1 = (const float*)d_in[6];
  const float* W2 = (const float*)d_in[7],  *root2 = (const float*)d_in[8],  *b2 = (const float*)d_in[9];
  const float* W3 = (const float*)d_in[10], *root3 = (const float*)d_in[11], *b3 = (const float*)d_in[12];
  const float* fw1 = (const float*)d_in[13], *fb1 = (const float*)d_in[14];
  const float* fw2 = (const float*)d_in[15], *fb2 = (const float*)d_in[16];
  float* out = (float*)d_out;

  // workspace layout (~155 MB)
  char* ws = (char*)d_ws;
  size_t off = 0;
  auto alloc = [&](size_t bytes) -> void* {
    void* p = ws + off; off += (bytes + 255) & ~(size_t)255; return p;
  };
  int*   cnt    = (int*)alloc(NBUCKET * 4);
  int*   offs   = (int*)alloc(NBUCKET * 4);
  int*   cursor = (int*)alloc(NBUCKET * 4);
  int*   eexcl  = (int*)alloc(NBUCKET * 4);
  int*   btot   = (int*)alloc(256 * 4);
  int*   elist  = (int*)alloc(N_EDGES * 4);
  float* inv    = (float*)alloc(NBUCKET * 4);
  unsigned short* Xcat  = (unsigned short*)alloc((size_t)N_NODES * 5120 * 2);
  unsigned short* WcatT = (unsigned short*)alloc((size_t)1024 * 5120 * 2);
  unsigned short* hA = (unsigned short*)alloc((size_t)N_NODES * 1024 * 2);
  unsigned short* hB = (unsigned short*)alloc((size_t)N_NODES * 1024 * 2);
  (void)ws_size;

  // CSR by (dst, rel)
  hipMemsetAsync(cnt, 0, NBUCKET * 4, stream);
  count_edges_k<<<(N_EDGES + 255) / 256, 256, 0, stream>>>(ei, et, cnt, N_EDGES);
  int nsb = (NBUCKET + 255) / 256;  // 157 blocks (<256)
  scan_block_k<<<nsb, 256, 0, stream>>>(cnt, eexcl, btot, NBUCKET);
  scan_final_k<<<nsb, 256, 0, stream>>>(cnt, eexcl, btot, offs, cursor, inv, NBUCKET);
  fill_csr_k<<<(N_EDGES + 255) / 256, 256, 0, stream>>>(ei, et, cursor, elist, N_EDGES);

  // layer 1: Din=64, K=320, F=1024, x -> hA
  wcat_transpose_k<<<dim3(10, 32), dim3(32, 8), 0, stream>>>(W1, root1, WcatT, 256, 1024, 320);
  aggregate64_k<<<N_NODES, 256, 0, stream>>>(x, offs, cnt, inv, elist, Xcat);
  gemm_bt_bias_relu_k<<<8 * 80, 256, 0, stream>>>(
      (const short*)Xcat, (const short*)WcatT, b1, hA, N_NODES, 1024, 320, 8);

  // layer 2: Din=1024, K=5120, F=1024, hA -> hB
  wcat_transpose_k<<<dim3(160, 32), dim3(32, 8), 0, stream>>>(W2, root2, WcatT, 4096, 1024, 5120);
  aggregate_bf16_k<<<N_NODES, 256, 0, stream>>>(hA, offs, cnt, inv, elist, Xcat);
  gemm_bt_bias_relu_k<<<8 * 80, 256, 0, stream>>>(
      (const short*)Xcat, (const short*)WcatT, b2, hB, N_NODES, 1024, 5120, 8);

  // layer 3: Din=1024, K=5120, F=712, hB -> hA (hA is dead, reuse)
  wcat_transpose_k<<<dim3(160, 23), dim3(32, 8), 0, stream>>>(W3, root3, WcatT, 4096, 712, 5120);
  aggregate_bf16_k<<<N_NODES, 256, 0, stream>>>(hB, offs, cnt, inv, elist, Xcat);
  gemm_bt_bias_relu_k<<<6 * 80, 256, 0, stream>>>(
      (const short*)Xcat, (const short*)WcatT, b3, hA, N_NODES, 712, 5120, 6);

  // fused pool + head
  pool_mlp_k<<<N_GRAPHS, 256, 0, stream>>>(hA, batch, fw1, fb1, fw2, fb2, out,
                                           N_NODES, 712);
}

// Round 3
// 549.598 us; speedup vs baseline: 1.0269x; 1.0269x over previous
//
#include <hip/hip_runtime.h>
#include <stdint.h>

#define N_NODES 10000
#define N_EDGES 160000
#define N_REL   4
#define N_GRAPHS 256
#define NBUCKET (N_NODES * N_REL)   // 40000 (dst,rel) buckets

typedef __attribute__((ext_vector_type(8))) short short8;
typedef __attribute__((ext_vector_type(4))) float float4v;

// ---------- helpers ----------
__device__ __forceinline__ unsigned short f2bf(float f) {
  unsigned int u = __float_as_uint(f);
  u = u + 0x7FFFu + ((u >> 16) & 1u);   // round-to-nearest-even
  return (unsigned short)(u >> 16);
}
__device__ __forceinline__ float bf2f(unsigned short b) {
  return __uint_as_float(((unsigned int)b) << 16);
}

__device__ __forceinline__ void g2lds16(const void* g, void* l) {
  // async global->LDS, 16B per lane; LDS dest = wave-uniform base + lane*16
  __builtin_amdgcn_global_load_lds(
      (const __attribute__((address_space(1))) void*)g,
      (__attribute__((address_space(3))) void*)l, 16, 0, 0);
}

__device__ __forceinline__ int lower_bound_i(const int* a, int n, int key) {
  int lo = 0, hi = n;
  while (lo < hi) { int mid = (lo + hi) >> 1; if (a[mid] < key) lo = mid + 1; else hi = mid; }
  return lo;
}

// ---------- CSR build ----------
__global__ void count_edges_k(const int* __restrict__ ei, const int* __restrict__ et,
                              int* __restrict__ cnt, int E) {
  int e = blockIdx.x * 256 + threadIdx.x;
  if (e < E) atomicAdd(&cnt[ei[E + e] * N_REL + et[e]], 1);
}

__global__ void scan_block_k(const int* __restrict__ cnt, int* __restrict__ eexcl,
                             int* __restrict__ btot, int n) {
  int i = blockIdx.x * 256 + threadIdx.x;
  int v = (i < n) ? cnt[i] : 0;
  int lane = threadIdx.x & 63, wv = threadIdx.x >> 6;
  int s = v;
  #pragma unroll
  for (int off = 1; off < 64; off <<= 1) {
    int t = __shfl_up(s, off, 64);
    if (lane >= off) s += t;
  }
  __shared__ int wt[4];
  if (lane == 63) wt[wv] = s;
  __syncthreads();
  int wadd = 0;
  for (int w = 0; w < wv; ++w) wadd += wt[w];
  int incl = s + wadd;
  if (i < n) eexcl[i] = incl - v;
  if (threadIdx.x == 255) btot[blockIdx.x] = incl;
}

__global__ void scan_final_k(const int* __restrict__ cnt, const int* __restrict__ eexcl,
                             const int* __restrict__ btot, int* __restrict__ offs,
                             int* __restrict__ cursor, float* __restrict__ inv, int n) {
  __shared__ int wred[4];
  __shared__ int sboff;
  int t = threadIdx.x;
  int part = (t < (int)blockIdx.x) ? btot[t] : 0;   // gridDim <= 256
  #pragma unroll
  for (int off = 32; off > 0; off >>= 1) part += __shfl_down(part, off, 64);
  if ((t & 63) == 0) wred[t >> 6] = part;
  __syncthreads();
  if (t == 0) sboff = wred[0] + wred[1] + wred[2] + wred[3];
  __syncthreads();
  int i = blockIdx.x * 256 + t;
  if (i < n) {
    int o = sboff + eexcl[i];
    offs[i] = o;
    cursor[i] = o;
    int c = cnt[i];
    inv[i] = 1.0f / (float)(c > 1 ? c : 1);
  }
}

__global__ void fill_csr_k(const int* __restrict__ ei, const int* __restrict__ et,
                           int* __restrict__ cursor, int* __restrict__ elist, int E) {
  int e = blockIdx.x * 256 + threadIdx.x;
  if (e >= E) return;
  int dst = ei[E + e], src = ei[e], r = et[e];
  int pos = atomicAdd(&cursor[dst * N_REL + r], 1);
  elist[pos] = src;
}

// ---------- wcat body: [F][K] bf16, K = 5*Din, rows 0..4Din-1 from W, rest from root ----
// tile is caller-provided LDS (fp32 [32][33]).
__device__ __forceinline__ void wcat_body(const float* __restrict__ W,
                                          const float* __restrict__ root,
                                          unsigned short* __restrict__ out,
                                          int Din4, int F, int K,
                                          int bx, int by, int tx, int ty,
                                          float (*tile)[33]) {
  int kb = bx * 32, fb = by * 32;
  for (int i = ty; i < 32; i += 8) {
    int k = kb + i, f = fb + tx;
    float v = 0.0f;
    if (k < K && f < F) v = (k < Din4) ? W[(size_t)k * F + f] : root[(size_t)(k - Din4) * F + f];
    tile[i][tx] = v;
  }
  __syncthreads();
  for (int i = ty; i < 32; i += 8) {
    int f = fb + i, k = kb + tx;
    if (f < F && k < K) out[(size_t)f * K + k] = f2bf(tile[tx][i]);
  }
}

// ---------- fused layer-1: agg (Din=64, fp32 x) blocks [0,10000) + wcat1 blocks ----------
// agg: one wave per (node, rel); serial j loop 2-wide unrolled (independent loads,
// in-order adds => bit-identical).
__global__ __launch_bounds__(256) void agg64_wcat_k(
    const float* __restrict__ x, const int* __restrict__ offs,
    const int* __restrict__ cnt, const float* __restrict__ inv,
    const int* __restrict__ elist, unsigned short* __restrict__ Xcat,
    const float* __restrict__ W, const float* __restrict__ root,
    unsigned short* __restrict__ WcatT, int wcatGX) {
  __shared__ float tile[32][33];
  if (blockIdx.x < N_NODES) {
    const int n = blockIdx.x;
    const int wv = threadIdx.x >> 6;    // relation
    const int col = threadIdx.x & 63;
    const int b = n * N_REL + wv;
    const int start = offs[b], c = cnt[b];
    const float sc = inv[b];
    float acc = 0.0f;
    int j = 0;
    for (; j + 2 <= c; j += 2) {
      int s0 = elist[start + j], s1 = elist[start + j + 1];
      float v0 = x[(size_t)s0 * 64 + col];
      float v1 = x[(size_t)s1 * 64 + col];
      acc += v0; acc += v1;
    }
    for (; j < c; ++j) {
      int s = elist[start + j];
      acc += x[(size_t)s * 64 + col];
    }
    Xcat[(size_t)n * 320 + wv * 64 + col] = f2bf(acc * sc);
    if (wv == 0)
      Xcat[(size_t)n * 320 + 256 + col] = f2bf(x[(size_t)n * 64 + col]);
  } else {
    int bb = blockIdx.x - N_NODES;
    int bx = bb % wcatGX, by = bb / wcatGX;
    wcat_body(W, root, WcatT, 256, 1024, 320, bx, by,
              threadIdx.x & 31, threadIdx.x >> 5, tile);
  }
}

// ---------- fused layer-2/3: agg (Din=1024, bf16 h) blocks [0,10000) + wcat blocks ----
// agg part: 4-wave blocks, 4 nodes x same 256-col chunk, no LDS/no barriers,
// 4-wide unrolled gather (4 independent 8B loads in flight). XCD slice
// pinning: chunk = (bid&7)>>1 => chunk-c blocks land on XCDs {2c,2c+1}
// (heuristic XCD = bid%8); each 10000x256x2B = 5.1MB slice stays ~L2-resident.
// Summation order per (node,rel,col) is ascending j into one accumulator =>
// bit-identical to the serial reference order.
__global__ __launch_bounds__(256) void aggbf16_wcat_k(
    const unsigned short* __restrict__ h,
    const int* __restrict__ offs, const int* __restrict__ cnt,
    const float* __restrict__ inv, const int* __restrict__ elist,
    unsigned short* __restrict__ Xcat,
    const float* __restrict__ W, const float* __restrict__ root,
    unsigned short* __restrict__ WcatT, int wcatGX, int Din4, int F, int K) {
  __shared__ float tile[32][33];
  if (blockIdx.x < N_NODES) {
    const int bid = blockIdx.x;
    const int chunk = (bid & 7) >> 1;
    const int wv = threadIdx.x >> 6;
    const int lane = threadIdx.x & 63;
    // bijective (node, chunk) mapping: n bit2 <- bid bit0, n bits[1:0] <- wave
    const int n = ((bid >> 3) << 3) | ((bid & 1) << 2) | wv;
    const int col = chunk * 256 + (lane << 2);    // 4 bf16 cols per lane (8B)
    const int Din = 1024, K5 = 5120;
    const int b0 = n * N_REL;

    #pragma unroll
    for (int r = 0; r < N_REL; ++r) {
      const int sr = offs[b0 + r];
      const int c = cnt[b0 + r];
      float a0 = 0.f, a1 = 0.f, a2 = 0.f, a3 = 0.f;
      int j = 0;
      for (; j + 4 <= c; j += 4) {
        const int s0 = elist[sr + j + 0];
        const int s1 = elist[sr + j + 1];
        const int s2 = elist[sr + j + 2];
        const int s3 = elist[sr + j + 3];
        ushort4 v0 = *(const ushort4*)(h + (size_t)s0 * Din + col);
        ushort4 v1 = *(const ushort4*)(h + (size_t)s1 * Din + col);
        ushort4 v2 = *(const ushort4*)(h + (size_t)s2 * Din + col);
        ushort4 v3 = *(const ushort4*)(h + (size_t)s3 * Din + col);
        a0 += bf2f(v0.x); a1 += bf2f(v0.y); a2 += bf2f(v0.z); a3 += bf2f(v0.w);
        a0 += bf2f(v1.x); a1 += bf2f(v1.y); a2 += bf2f(v1.z); a3 += bf2f(v1.w);
        a0 += bf2f(v2.x); a1 += bf2f(v2.y); a2 += bf2f(v2.z); a3 += bf2f(v2.w);
        a0 += bf2f(v3.x); a1 += bf2f(v3.y); a2 += bf2f(v3.z); a3 += bf2f(v3.w);
      }
      for (; j < c; ++j) {
        const int s = elist[sr + j];
        ushort4 v = *(const ushort4*)(h + (size_t)s * Din + col);
        a0 += bf2f(v.x); a1 += bf2f(v.y); a2 += bf2f(v.z); a3 += bf2f(v.w);
      }
      const float sc = inv[b0 + r];
      ushort4 o;
      o.x = f2bf(a0 * sc); o.y = f2bf(a1 * sc);
      o.z = f2bf(a2 * sc); o.w = f2bf(a3 * sc);
      *(ushort4*)&Xcat[(size_t)n * K5 + r * Din + col] = o;
    }
    // root block: copy h[n] bits directly
    *(ushort4*)&Xcat[(size_t)n * K5 + 4 * Din + col] =
        *(const ushort4*)(h + (size_t)n * Din + col);
  } else {
    int bb = blockIdx.x - N_NODES;
    int bx = bb % wcatGX, by = bb / wcatGX;
    wcat_body(W, root, WcatT, Din4, F, K, bx, by,
              threadIdx.x & 31, threadIdx.x >> 5, tile);
  }
}

// ---------- GEMM: C[M,F](bf16) = relu(A[M,K](bf16) @ Bt[F,K]^T(bf16) + bias) ----------
// BK=64, XOR-swizzled LDS (conflict-free, verified: SQ_LDS_BANK_CONFLICT=0).
// 1D grid = NX*80 blocks, XCD-banded mapping: xcd = bid%8 owns 10 contiguous
// row-strips x all NX columns, so each A-strip is fetched once per XCD and
// reused NX times from its L2. Known remaining loss: 640 blocks @ 2.5/CU means
// half the CUs carry 3 tiles vs 2.5 avg => ~1.2x tail (681 TF effective vs
// ~912 balanced ceiling of this structure).
__global__ __launch_bounds__(256) void gemm_bt_bias_relu_k(
    const short* __restrict__ A, const short* __restrict__ Bt,
    const float* __restrict__ bias, unsigned short* __restrict__ C,
    int M, int Ndim, int K, int NX) {
  __shared__ short As[128 * 64];   // 16 KB
  __shared__ short Bs[128 * 64];   // 16 KB

  const int bid = blockIdx.x;
  const int xcd = bid & 7;
  const int local = bid >> 3;              // [0, NX*10)
  const int t = xcd * (NX * 10) + local;   // contiguous tile band per XCD
  const int tileM = t / NX;                // [0, 80)
  const int tileN = t - tileM * NX;
  const int mBase = tileM * 128;
  const int nBase = tileN * 128;

  const int tid = threadIdx.x;
  const int wave = tid >> 6;
  const int lane = tid & 63;
  const int half = lane >> 4;     // k-quad 0..3
  const int lrow = lane & 15;
  const int wm = (wave >> 1) * 64;
  const int wn = (wave & 1) * 64;
  const int srow = lane >> 3;               // staging: row within 8-row group
  const int schunk = (lane & 7) ^ srow;     // swizzle: global chunk for this slot

  float4v acc[4][4] = {};

  for (int k0 = 0; k0 < K; k0 += 64) {
    #pragma unroll
    for (int p = 0; p < 4; ++p) {
      int rb = wave * 32 + p * 8;
      int r = rb + srow;
      int gr = mBase + r; if (gr > M - 1) gr = M - 1;
      g2lds16(A + (size_t)gr * K + k0 + schunk * 8, &As[rb * 64]);
      int gn = nBase + r; if (gn > Ndim - 1) gn = Ndim - 1;
      g2lds16(Bt + (size_t)gn * K + k0 + schunk * 8, &Bs[rb * 64]);
    }
    __syncthreads();

    #pragma unroll
    for (int kk = 0; kk < 2; ++kk) {
      short8 a[4], b[4];
      #pragma unroll
      for (int i = 0; i < 4; ++i) {
        int r = wm + i * 16 + lrow;
        int q = (kk * 4 + half) ^ (r & 7);
        a[i] = *(const short8*)&As[r * 64 + q * 8];
      }
      #pragma unroll
      for (int j = 0; j < 4; ++j) {
        int r = wn + j * 16 + lrow;
        int q = (kk * 4 + half) ^ (r & 7);
        b[j] = *(const short8*)&Bs[r * 64 + q * 8];
      }
      #pragma unroll
      for (int i = 0; i < 4; ++i)
        #pragma unroll
        for (int j = 0; j < 4; ++j)
          acc[i][j] = __builtin_amdgcn_mfma_f32_16x16x32_bf16(a[i], b[j], acc[i][j], 0, 0, 0);
    }
    __syncthreads();
  }

  #pragma unroll
  for (int i = 0; i < 4; ++i) {
    int row0 = mBase + wm + i * 16 + half * 4;
    #pragma unroll
    for (int j = 0; j < 4; ++j) {
      int col = nBase + wn + j * 16 + lrow;
      if (col < Ndim) {
        float bv = bias[col];
        #pragma unroll
        for (int r = 0; r < 4; ++r) {
          int rr = row0 + r;
          if (rr < M) C[(size_t)rr * Ndim + col] = f2bf(fmaxf(acc[i][j][r] + bv, 0.0f));
        }
      }
    }
  }
}

// ---------- fused pool + head MLP: one block per graph (bf16 h) ----------
__global__ __launch_bounds__(256) void pool_mlp_k(
    const unsigned short* __restrict__ h, const int* __restrict__ batch,
    const float* __restrict__ fw1, const float* __restrict__ fb1,
    const float* __restrict__ fw2, const float* __restrict__ fb2,
    float* __restrict__ out, int N, int F) {
  __shared__ float gsh[712];
  __shared__ float part[4][64];

  const int gid = blockIdx.x;
  const int tid = threadIdx.x;
  const int lo = lower_bound_i(batch, N, gid);
  const int hi = lower_bound_i(batch, N, gid + 1);
  const float scale = (hi > lo) ? 1.0f / (float)(hi - lo) : 0.0f;
  const int C4 = F >> 2;  // 178

  // stage 1: pooled mean into LDS
  if (tid < C4) {
    float a0 = 0.f, a1 = 0.f, a2 = 0.f, a3 = 0.f;
    for (int n = lo; n < hi; ++n) {
      ushort4 v = *(const ushort4*)(h + (size_t)n * F + tid * 4);
      a0 += bf2f(v.x); a1 += bf2f(v.y); a2 += bf2f(v.z); a3 += bf2f(v.w);
    }
    gsh[tid * 4 + 0] = a0 * scale;
    gsh[tid * 4 + 1] = a1 * scale;
    gsh[tid * 4 + 2] = a2 * scale;
    gsh[tid * 4 + 3] = a3 * scale;
  }
  __syncthreads();

  // stage 2: hidden-layer partial dot; f = lane, chunk = wave
  const int f = tid & 63;
  const int wv = tid >> 6;
  const int d0 = wv * 178;
  const int d1 = min(d0 + 178, F);
  float a = 0.0f;
  int d = d0;
  for (; d + 3 < d1; d += 4) {
    float g0 = gsh[d], g1 = gsh[d + 1], g2 = gsh[d + 2], g3 = gsh[d + 3];
    a += g0 * fw1[(size_t)d * 64 + f]
       + g1 * fw1[(size_t)(d + 1) * 64 + f]
       + g2 * fw1[(size_t)(d + 2) * 64 + f]
       + g3 * fw1[(size_t)(d + 3) * 64 + f];
  }
  for (; d < d1; ++d) a += gsh[d] * fw1[(size_t)d * 64 + f];
  part[wv][f] = a;
  __syncthreads();

  // stage 3: wave 0 reduces and finishes
  if (tid < 64) {
    float hsum = part[0][tid] + part[1][tid] + part[2][tid] + part[3][tid] + fb1[tid];
    hsum = fmaxf(hsum, 0.0f);
    float p = hsum * fw2[tid];
    #pragma unroll
    for (int off = 32; off > 0; off >>= 1) p += __shfl_down(p, off, 64);
    if (tid == 0) out[gid] = p + fb2[0];
  }
}

// ---------- launch ----------
extern "C" void kernel_launch(void* const* d_in, const int* in_sizes, int n_in,
                              void* d_out, int out_size, void* d_ws, size_t ws_size,
                              hipStream_t stream) {
  (void)in_sizes; (void)n_in; (void)out_size;
  const float* x    = (const float*)d_in[0];
  const int*  ei    = (const int*)d_in[1];
  const int*  et    = (const int*)d_in[2];
  const int*  batch = (const int*)d_in[3];
  const float* W1 = (const float*)d_in[4],  *root1 = (const float*)d_in[5],  *b1 = (const float*)d_in[6];
  const float* W2 = (const float*)d_in[7],  *root2 = (const float*)d_in[8],  *b2 = (const float*)d_in[9];
  const float* W3 = (const float*)d_in[10], *root3 = (const float*)d_in[11], *b3 = (const float*)d_in[12];
  const float* fw1 = (const float*)d_in[13], *fb1 = (const float*)d_in[14];
  const float* fw2 = (const float*)d_in[15], *fb2 = (const float*)d_in[16];
  float* out = (float*)d_out;

  // workspace layout (~155 MB)
  char* ws = (char*)d_ws;
  size_t off = 0;
  auto alloc = [&](size_t bytes) -> void* {
    void* p = ws + off; off += (bytes + 255) & ~(size_t)255; return p;
  };
  int*   cnt    = (int*)alloc(NBUCKET * 4);
  int*   offs   = (int*)alloc(NBUCKET * 4);
  int*   cursor = (int*)alloc(NBUCKET * 4);
  int*   eexcl  = (int*)alloc(NBUCKET * 4);
  int*   btot   = (int*)alloc(256 * 4);
  int*   elist  = (int*)alloc(N_EDGES * 4);
  float* inv    = (float*)alloc(NBUCKET * 4);
  unsigned short* Xcat  = (unsigned short*)alloc((size_t)N_NODES * 5120 * 2);
  unsigned short* WcatT = (unsigned short*)alloc((size_t)1024 * 5120 * 2);
  unsigned short* hA = (unsigned short*)alloc((size_t)N_NODES * 1024 * 2);
  unsigned short* hB = (unsigned short*)alloc((size_t)N_NODES * 1024 * 2);
  (void)ws_size;

  // CSR by (dst, rel)
  hipMemsetAsync(cnt, 0, NBUCKET * 4, stream);
  count_edges_k<<<(N_EDGES + 255) / 256, 256, 0, stream>>>(ei, et, cnt, N_EDGES);
  int nsb = (NBUCKET + 255) / 256;  // 157 blocks (<256)
  scan_block_k<<<nsb, 256, 0, stream>>>(cnt, eexcl, btot, NBUCKET);
  scan_final_k<<<nsb, 256, 0, stream>>>(cnt, eexcl, btot, offs, cursor, inv, NBUCKET);
  fill_csr_k<<<(N_EDGES + 255) / 256, 256, 0, stream>>>(ei, et, cursor, elist, N_EDGES);

  // layer 1: Din=64, K=320, F=1024, x -> hA   (agg64 + wcat1 fused)
  agg64_wcat_k<<<N_NODES + 10 * 32, 256, 0, stream>>>(
      x, offs, cnt, inv, elist, Xcat, W1, root1, WcatT, 10);
  gemm_bt_bias_relu_k<<<8 * 80, 256, 0, stream>>>(
      (const short*)Xcat, (const short*)WcatT, b1, hA, N_NODES, 1024, 320, 8);

  // layer 2: Din=1024, K=5120, F=1024, hA -> hB   (agg2 + wcat2 fused)
  aggbf16_wcat_k<<<N_NODES + 160 * 32, 256, 0, stream>>>(
      hA, offs, cnt, inv, elist, Xcat, W2, root2, WcatT, 160, 4096, 1024, 5120);
  gemm_bt_bias_relu_k<<<8 * 80, 256, 0, stream>>>(
      (const short*)Xcat, (const short*)WcatT, b2, hB, N_NODES, 1024, 5120, 8);

  // layer 3: Din=1024, K=5120, F=712, hB -> hA (hA is dead, reuse)  (agg3 + wcat3 fused)
  aggbf16_wcat_k<<<N_NODES + 160 * 23, 256, 0, stream>>>(
      hB, offs, cnt, inv, elist, Xcat, W3, root3, WcatT, 160, 4096, 712, 5120);
  gemm_bt_bias_relu_k<<<6 * 80, 256, 0, stream>>>(
      (const short*)Xcat, (const short*)WcatT, b3, hA, N_NODES, 712, 5120, 6);

  // fused pool + head
  pool_mlp_k<<<N_GRAPHS, 256, 0, stream>>>(hA, batch, fw1, fb1, fw2, fb2, out,
                                           N_NODES, 712);
}

// Round 4
// 545.853 us; speedup vs baseline: 1.0340x; 1.0069x over previous
//
#include <hip/hip_runtime.h>
#include <stdint.h>

#define N_NODES 10000
#define N_EDGES 160000
#define N_REL   4
#define N_GRAPHS 256
#define NBUCKET (N_NODES * N_REL)   // 40000 (dst,rel) buckets

typedef __attribute__((ext_vector_type(8))) short short8;
typedef __attribute__((ext_vector_type(4))) float float4v;

// ---------- helpers ----------
__device__ __forceinline__ unsigned short f2bf(float f) {
  unsigned int u = __float_as_uint(f);
  u = u + 0x7FFFu + ((u >> 16) & 1u);   // round-to-nearest-even
  return (unsigned short)(u >> 16);
}
__device__ __forceinline__ float bf2f(unsigned short b) {
  return __uint_as_float(((unsigned int)b) << 16);
}

__device__ __forceinline__ void g2lds16(const void* g, void* l) {
  // async global->LDS, 16B per lane; LDS dest = wave-uniform base + lane*16
  __builtin_amdgcn_global_load_lds(
      (const __attribute__((address_space(1))) void*)g,
      (__attribute__((address_space(3))) void*)l, 16, 0, 0);
}

__device__ __forceinline__ int lower_bound_i(const int* a, int n, int key) {
  int lo = 0, hi = n;
  while (lo < hi) { int mid = (lo + hi) >> 1; if (a[mid] < key) lo = mid + 1; else hi = mid; }
  return lo;
}

// ---------- CSR build ----------
__global__ void count_edges_k(const int* __restrict__ ei, const int* __restrict__ et,
                              int* __restrict__ cnt, int E) {
  int e = blockIdx.x * 256 + threadIdx.x;
  if (e < E) atomicAdd(&cnt[ei[E + e] * N_REL + et[e]], 1);
}

__global__ void scan_block_k(const int* __restrict__ cnt, int* __restrict__ eexcl,
                             int* __restrict__ btot, int n) {
  int i = blockIdx.x * 256 + threadIdx.x;
  int v = (i < n) ? cnt[i] : 0;
  int lane = threadIdx.x & 63, wv = threadIdx.x >> 6;
  int s = v;
  #pragma unroll
  for (int off = 1; off < 64; off <<= 1) {
    int t = __shfl_up(s, off, 64);
    if (lane >= off) s += t;
  }
  __shared__ int wt[4];
  if (lane == 63) wt[wv] = s;
  __syncthreads();
  int wadd = 0;
  for (int w = 0; w < wv; ++w) wadd += wt[w];
  int incl = s + wadd;
  if (i < n) eexcl[i] = incl - v;
  if (threadIdx.x == 255) btot[blockIdx.x] = incl;
}

__global__ void scan_final_k(const int* __restrict__ cnt, const int* __restrict__ eexcl,
                             const int* __restrict__ btot, int* __restrict__ offs,
                             int* __restrict__ cursor, float* __restrict__ inv, int n) {
  __shared__ int wred[4];
  __shared__ int sboff;
  int t = threadIdx.x;
  int part = (t < (int)blockIdx.x) ? btot[t] : 0;   // gridDim <= 256
  #pragma unroll
  for (int off = 32; off > 0; off >>= 1) part += __shfl_down(part, off, 64);
  if ((t & 63) == 0) wred[t >> 6] = part;
  __syncthreads();
  if (t == 0) sboff = wred[0] + wred[1] + wred[2] + wred[3];
  __syncthreads();
  int i = blockIdx.x * 256 + t;
  if (i < n) {
    int o = sboff + eexcl[i];
    offs[i] = o;
    cursor[i] = o;
    int c = cnt[i];
    inv[i] = 1.0f / (float)(c > 1 ? c : 1);
  }
}

__global__ void fill_csr_k(const int* __restrict__ ei, const int* __restrict__ et,
                           int* __restrict__ cursor, int* __restrict__ elist, int E) {
  int e = blockIdx.x * 256 + threadIdx.x;
  if (e >= E) return;
  int dst = ei[E + e], src = ei[e], r = et[e];
  int pos = atomicAdd(&cursor[dst * N_REL + r], 1);
  elist[pos] = src;
}

// ---------- wcat body: [F][K] bf16, K = 5*Din, rows 0..4Din-1 from W, rest from root ----
// tile is caller-provided LDS (fp32 [32][33]).
__device__ __forceinline__ void wcat_body(const float* __restrict__ W,
                                          const float* __restrict__ root,
                                          unsigned short* __restrict__ out,
                                          int Din4, int F, int K,
                                          int bx, int by, int tx, int ty,
                                          float (*tile)[33]) {
  int kb = bx * 32, fb = by * 32;
  for (int i = ty; i < 32; i += 8) {
    int k = kb + i, f = fb + tx;
    float v = 0.0f;
    if (k < K && f < F) v = (k < Din4) ? W[(size_t)k * F + f] : root[(size_t)(k - Din4) * F + f];
    tile[i][tx] = v;
  }
  __syncthreads();
  for (int i = ty; i < 32; i += 8) {
    int f = fb + i, k = kb + tx;
    if (f < F && k < K) out[(size_t)f * K + k] = f2bf(tile[tx][i]);
  }
}

// ---------- fused layer-1: agg (Din=64, fp32 x) blocks [0,10000) + wcat1 blocks ----------
// agg: one wave per (node, rel); serial j loop 2-wide unrolled (independent loads,
// in-order adds => bit-identical).
__global__ __launch_bounds__(256) void agg64_wcat_k(
    const float* __restrict__ x, const int* __restrict__ offs,
    const int* __restrict__ cnt, const float* __restrict__ inv,
    const int* __restrict__ elist, unsigned short* __restrict__ Xcat,
    const float* __restrict__ W, const float* __restrict__ root,
    unsigned short* __restrict__ WcatT, int wcatGX) {
  __shared__ float tile[32][33];
  if (blockIdx.x < N_NODES) {
    const int n = blockIdx.x;
    const int wv = threadIdx.x >> 6;    // relation
    const int col = threadIdx.x & 63;
    const int b = n * N_REL + wv;
    const int start = offs[b], c = cnt[b];
    const float sc = inv[b];
    float acc = 0.0f;
    int j = 0;
    for (; j + 2 <= c; j += 2) {
      int s0 = elist[start + j], s1 = elist[start + j + 1];
      float v0 = x[(size_t)s0 * 64 + col];
      float v1 = x[(size_t)s1 * 64 + col];
      acc += v0; acc += v1;
    }
    for (; j < c; ++j) {
      int s = elist[start + j];
      acc += x[(size_t)s * 64 + col];
    }
    Xcat[(size_t)n * 320 + wv * 64 + col] = f2bf(acc * sc);
    if (wv == 0)
      Xcat[(size_t)n * 320 + 256 + col] = f2bf(x[(size_t)n * 64 + col]);
  } else {
    int bb = blockIdx.x - N_NODES;
    int bx = bb % wcatGX, by = bb / wcatGX;
    wcat_body(W, root, WcatT, 256, 1024, 320, bx, by,
              threadIdx.x & 31, threadIdx.x >> 5, tile);
  }
}

// ---------- pure aggregation (Din=1024, bf16 h), column-sliced for L2 residency ----------
// Writes ONLY the 4 aggregated rel blocks (stride 4096); the root block is read
// directly from h by the GEMM's A-staging (saves 41 MB copy traffic per layer).
// 4-wave blocks, 4 nodes x same 256-col chunk, no LDS/no barriers, 4-wide
// unrolled gather. XCD slice pinning: chunk = (bid&7)>>1 => chunk-c blocks land
// on XCDs {2c,2c+1} (heuristic XCD = bid%8); each 10000x256x2B = 5.1MB slice
// stays ~L2-resident. Summation order per (node,rel,col) is ascending j into
// one accumulator => bit-identical.
__global__ __launch_bounds__(256) void aggbf16_k(
    const unsigned short* __restrict__ h,
    const int* __restrict__ offs, const int* __restrict__ cnt,
    const float* __restrict__ inv, const int* __restrict__ elist,
    unsigned short* __restrict__ Xcat) {
  const int bid = blockIdx.x;
  const int chunk = (bid & 7) >> 1;
  const int wv = threadIdx.x >> 6;
  const int lane = threadIdx.x & 63;
  // bijective (node, chunk) mapping: n bit2 <- bid bit0, n bits[1:0] <- wave
  const int n = ((bid >> 3) << 3) | ((bid & 1) << 2) | wv;
  const int col = chunk * 256 + (lane << 2);    // 4 bf16 cols per lane (8B)
  const int Din = 1024, KA = 4096;
  const int b0 = n * N_REL;

  #pragma unroll
  for (int r = 0; r < N_REL; ++r) {
    const int sr = offs[b0 + r];
    const int c = cnt[b0 + r];
    float a0 = 0.f, a1 = 0.f, a2 = 0.f, a3 = 0.f;
    int j = 0;
    for (; j + 4 <= c; j += 4) {
      const int s0 = elist[sr + j + 0];
      const int s1 = elist[sr + j + 1];
      const int s2 = elist[sr + j + 2];
      const int s3 = elist[sr + j + 3];
      ushort4 v0 = *(const ushort4*)(h + (size_t)s0 * Din + col);
      ushort4 v1 = *(const ushort4*)(h + (size_t)s1 * Din + col);
      ushort4 v2 = *(const ushort4*)(h + (size_t)s2 * Din + col);
      ushort4 v3 = *(const ushort4*)(h + (size_t)s3 * Din + col);
      a0 += bf2f(v0.x); a1 += bf2f(v0.y); a2 += bf2f(v0.z); a3 += bf2f(v0.w);
      a0 += bf2f(v1.x); a1 += bf2f(v1.y); a2 += bf2f(v1.z); a3 += bf2f(v1.w);
      a0 += bf2f(v2.x); a1 += bf2f(v2.y); a2 += bf2f(v2.z); a3 += bf2f(v2.w);
      a0 += bf2f(v3.x); a1 += bf2f(v3.y); a2 += bf2f(v3.z); a3 += bf2f(v3.w);
    }
    for (; j < c; ++j) {
      const int s = elist[sr + j];
      ushort4 v = *(const ushort4*)(h + (size_t)s * Din + col);
      a0 += bf2f(v.x); a1 += bf2f(v.y); a2 += bf2f(v.z); a3 += bf2f(v.w);
    }
    const float sc = inv[b0 + r];
    ushort4 o;
    o.x = f2bf(a0 * sc); o.y = f2bf(a1 * sc);
    o.z = f2bf(a2 * sc); o.w = f2bf(a3 * sc);
    *(ushort4*)&Xcat[(size_t)n * KA + r * Din + col] = o;
  }
}

// ---------- GEMM: C[M,F](bf16) = relu(A' @ Bt^T + bias) ----------
// A' row n: k<aggK from A (stride KA); k>=aggK from rootA (stride 1024 = h row).
// BK=64, XOR-swizzled LDS (conflict-free, verified: SQ_LDS_BANK_CONFLICT=0).
// gemm blocks [0,gemmNB): NX*80 blocks, XCD-banded (xcd = bid%8 owns 10
// contiguous row-strips x all NX cols -> A-strip fetched ~once per XCD L2).
// blocks [gemmNB, +): wcat transpose for the NEXT layer's weights (tail-fill
// overlap; writes a ping-pong Wcat buffer, never the one this gemm reads).
__global__ __launch_bounds__(256) void gemm_bt_bias_relu_k(
    const short* __restrict__ A, int KA,
    const short* __restrict__ rootA, int aggK,
    const short* __restrict__ Bt,
    const float* __restrict__ bias, unsigned short* __restrict__ C,
    int M, int Ndim, int K, int NX, int gemmNB,
    const float* __restrict__ wW, const float* __restrict__ wRoot,
    unsigned short* __restrict__ wOut, int wGX, int wDin4, int wF, int wK) {
  __shared__ short As[128 * 64];   // 16 KB
  __shared__ short Bs[128 * 64];   // 16 KB

  if ((int)blockIdx.x >= gemmNB) {
    // wcat tail blocks: reuse As as the fp32 [32][33] transpose tile (4.2 KB)
    int bb = blockIdx.x - gemmNB;
    float (*tile)[33] = (float (*)[33])As;
    wcat_body(wW, wRoot, wOut, wDin4, wF, wK, bb % wGX, bb / wGX,
              threadIdx.x & 31, threadIdx.x >> 5, tile);
    return;
  }

  const int bid = blockIdx.x;
  const int xcd = bid & 7;
  const int local = bid >> 3;              // [0, NX*10)
  const int t = xcd * (NX * 10) + local;   // contiguous tile band per XCD
  const int tileM = t / NX;                // [0, 80)
  const int tileN = t - tileM * NX;
  const int mBase = tileM * 128;
  const int nBase = tileN * 128;

  const int tid = threadIdx.x;
  const int wave = tid >> 6;
  const int lane = tid & 63;
  const int half = lane >> 4;     // k-quad 0..3
  const int lrow = lane & 15;
  const int wm = (wave >> 1) * 64;
  const int wn = (wave & 1) * 64;
  const int srow = lane >> 3;               // staging: row within 8-row group
  const int schunk = (lane & 7) ^ srow;     // swizzle: global chunk for this slot

  float4v acc[4][4] = {};

  for (int k0 = 0; k0 < K; k0 += 64) {
    #pragma unroll
    for (int p = 0; p < 4; ++p) {
      int rb = wave * 32 + p * 8;
      int r = rb + srow;
      int gr = mBase + r; if (gr > M - 1) gr = M - 1;
      const short* aSrc;
      if (k0 < aggK) aSrc = A + (size_t)gr * KA + k0;
      else           aSrc = rootA + (size_t)gr * 1024 + (k0 - aggK);
      g2lds16(aSrc + schunk * 8, &As[rb * 64]);
      int gn = nBase + r; if (gn > Ndim - 1) gn = Ndim - 1;
      g2lds16(Bt + (size_t)gn * K + k0 + schunk * 8, &Bs[rb * 64]);
    }
    __syncthreads();

    #pragma unroll
    for (int kk = 0; kk < 2; ++kk) {
      short8 a[4], b[4];
      #pragma unroll
      for (int i = 0; i < 4; ++i) {
        int r = wm + i * 16 + lrow;
        int q = (kk * 4 + half) ^ (r & 7);
        a[i] = *(const short8*)&As[r * 64 + q * 8];
      }
      #pragma unroll
      for (int j = 0; j < 4; ++j) {
        int r = wn + j * 16 + lrow;
        int q = (kk * 4 + half) ^ (r & 7);
        b[j] = *(const short8*)&Bs[r * 64 + q * 8];
      }
      #pragma unroll
      for (int i = 0; i < 4; ++i)
        #pragma unroll
        for (int j = 0; j < 4; ++j)
          acc[i][j] = __builtin_amdgcn_mfma_f32_16x16x32_bf16(a[i], b[j], acc[i][j], 0, 0, 0);
    }
    __syncthreads();
  }

  #pragma unroll
  for (int i = 0; i < 4; ++i) {
    int row0 = mBase + wm + i * 16 + half * 4;
    #pragma unroll
    for (int j = 0; j < 4; ++j) {
      int col = nBase + wn + j * 16 + lrow;
      if (col < Ndim) {
        float bv = bias[col];
        #pragma unroll
        for (int r = 0; r < 4; ++r) {
          int rr = row0 + r;
          if (rr < M) C[(size_t)rr * Ndim + col] = f2bf(fmaxf(acc[i][j][r] + bv, 0.0f));
        }
      }
    }
  }
}

// ---------- fused pool + head MLP: one block per graph (bf16 h) ----------
__global__ __launch_bounds__(256) void pool_mlp_k(
    const unsigned short* __restrict__ h, const int* __restrict__ batch,
    const float* __restrict__ fw1, const float* __restrict__ fb1,
    const float* __restrict__ fw2, const float* __restrict__ fb2,
    float* __restrict__ out, int N, int F) {
  __shared__ float gsh[712];
  __shared__ float part[4][64];

  const int gid = blockIdx.x;
  const int tid = threadIdx.x;
  const int lo = lower_bound_i(batch, N, gid);
  const int hi = lower_bound_i(batch, N, gid + 1);
  const float scale = (hi > lo) ? 1.0f / (float)(hi - lo) : 0.0f;
  const int C4 = F >> 2;  // 178

  // stage 1: pooled mean into LDS
  if (tid < C4) {
    float a0 = 0.f, a1 = 0.f, a2 = 0.f, a3 = 0.f;
    for (int n = lo; n < hi; ++n) {
      ushort4 v = *(const ushort4*)(h + (size_t)n * F + tid * 4);
      a0 += bf2f(v.x); a1 += bf2f(v.y); a2 += bf2f(v.z); a3 += bf2f(v.w);
    }
    gsh[tid * 4 + 0] = a0 * scale;
    gsh[tid * 4 + 1] = a1 * scale;
    gsh[tid * 4 + 2] = a2 * scale;
    gsh[tid * 4 + 3] = a3 * scale;
  }
  __syncthreads();

  // stage 2: hidden-layer partial dot; f = lane, chunk = wave
  const int f = tid & 63;
  const int wv = tid >> 6;
  const int d0 = wv * 178;
  const int d1 = min(d0 + 178, F);
  float a = 0.0f;
  int d = d0;
  for (; d + 3 < d1; d += 4) {
    float g0 = gsh[d], g1 = gsh[d + 1], g2 = gsh[d + 2], g3 = gsh[d + 3];
    a += g0 * fw1[(size_t)d * 64 + f]
       + g1 * fw1[(size_t)(d + 1) * 64 + f]
       + g2 * fw1[(size_t)(d + 2) * 64 + f]
       + g3 * fw1[(size_t)(d + 3) * 64 + f];
  }
  for (; d < d1; ++d) a += gsh[d] * fw1[(size_t)d * 64 + f];
  part[wv][f] = a;
  __syncthreads();

  // stage 3: wave 0 reduces and finishes
  if (tid < 64) {
    float hsum = part[0][tid] + part[1][tid] + part[2][tid] + part[3][tid] + fb1[tid];
    hsum = fmaxf(hsum, 0.0f);
    float p = hsum * fw2[tid];
    #pragma unroll
    for (int off = 32; off > 0; off >>= 1) p += __shfl_down(p, off, 64);
    if (tid == 0) out[gid] = p + fb2[0];
  }
}

// ---------- launch ----------
extern "C" void kernel_launch(void* const* d_in, const int* in_sizes, int n_in,
                              void* d_out, int out_size, void* d_ws, size_t ws_size,
                              hipStream_t stream) {
  (void)in_sizes; (void)n_in; (void)out_size;
  const float* x    = (const float*)d_in[0];
  const int*  ei    = (const int*)d_in[1];
  const int*  et    = (const int*)d_in[2];
  const int*  batch = (const int*)d_in[3];
  const float* W1 = (const float*)d_in[4],  *root1 = (const float*)d_in[5],  *b1 = (const float*)d_in[6];
  const float* W2 = (const float*)d_in[7],  *root2 = (const float*)d_in[8],  *b2 = (const float*)d_in[9];
  const float* W3 = (const float*)d_in[10], *root3 = (const float*)d_in[11], *b3 = (const float*)d_in[12];
  const float* fw1 = (const float*)d_in[13], *fb1 = (const float*)d_in[14];
  const float* fw2 = (const float*)d_in[15], *fb2 = (const float*)d_in[16];
  float* out = (float*)d_out;

  // workspace layout (~142 MB)
  char* ws = (char*)d_ws;
  size_t off = 0;
  auto alloc = [&](size_t bytes) -> void* {
    void* p = ws + off; off += (bytes + 255) & ~(size_t)255; return p;
  };
  int*   cnt    = (int*)alloc(NBUCKET * 4);
  int*   offs   = (int*)alloc(NBUCKET * 4);
  int*   cursor = (int*)alloc(NBUCKET * 4);
  int*   eexcl  = (int*)alloc(NBUCKET * 4);
  int*   btot   = (int*)alloc(256 * 4);
  int*   elist  = (int*)alloc(N_EDGES * 4);
  float* inv    = (float*)alloc(NBUCKET * 4);
  unsigned short* Xcat  = (unsigned short*)alloc((size_t)N_NODES * 4096 * 2);  // 78 MB
  unsigned short* WcatA = (unsigned short*)alloc((size_t)1024 * 5120 * 2);     // 10.5 MB
  unsigned short* WcatB = (unsigned short*)alloc((size_t)1024 * 5120 * 2);     // 10.5 MB
  unsigned short* hA = (unsigned short*)alloc((size_t)N_NODES * 1024 * 2);
  unsigned short* hB = (unsigned short*)alloc((size_t)N_NODES * 1024 * 2);
  (void)ws_size;

  // CSR by (dst, rel)
  hipMemsetAsync(cnt, 0, NBUCKET * 4, stream);
  count_edges_k<<<(N_EDGES + 255) / 256, 256, 0, stream>>>(ei, et, cnt, N_EDGES);
  int nsb = (NBUCKET + 255) / 256;  // 157 blocks (<256)
  scan_block_k<<<nsb, 256, 0, stream>>>(cnt, eexcl, btot, NBUCKET);
  scan_final_k<<<nsb, 256, 0, stream>>>(cnt, eexcl, btot, offs, cursor, inv, NBUCKET);
  fill_csr_k<<<(N_EDGES + 255) / 256, 256, 0, stream>>>(ei, et, cursor, elist, N_EDGES);

  // layer 1: Din=64, K=320, F=1024, x -> hA   (agg64 + wcat1 -> WcatA)
  agg64_wcat_k<<<N_NODES + 10 * 32, 256, 0, stream>>>(
      x, offs, cnt, inv, elist, Xcat, W1, root1, WcatA, 10);
  // gemm1 (A = Xcat stride 320, no root path) + wcat2 -> WcatB (tail-fill)
  gemm_bt_bias_relu_k<<<8 * 80 + 160 * 32, 256, 0, stream>>>(
      (const short*)Xcat, 320, nullptr, 320,
      (const short*)WcatA, b1, hA, N_NODES, 1024, 320, 8, 8 * 80,
      W2, root2, WcatB, 160, 4096, 1024, 5120);

  // layer 2: Din=1024, K=5120 (agg 4096 + root from hA), F=1024, hA -> hB
  aggbf16_k<<<N_NODES, 256, 0, stream>>>(hA, offs, cnt, inv, elist, Xcat);
  // gemm2 + wcat3 -> WcatA (tail-fill)
  gemm_bt_bias_relu_k<<<8 * 80 + 160 * 23, 256, 0, stream>>>(
      (const short*)Xcat, 4096, (const short*)hA, 4096,
      (const short*)WcatB, b2, hB, N_NODES, 1024, 5120, 8, 8 * 80,
      W3, root3, WcatA, 160, 4096, 712, 5120);

  // layer 3: Din=1024, K=5120 (agg 4096 + root from hB), F=712, hB -> hA
  aggbf16_k<<<N_NODES, 256, 0, stream>>>(hB, offs, cnt, inv, elist, Xcat);
  gemm_bt_bias_relu_k<<<6 * 80, 256, 0, stream>>>(
      (const short*)Xcat, 4096, (const short*)hB, 4096,
      (const short*)WcatA, b3, hA, N_NODES, 712, 5120, 6, 6 * 80,
      nullptr, nullptr, nullptr, 1, 0, 0, 0);

  // fused pool + head
  pool_mlp_k<<<N_GRAPHS, 256, 0, stream>>>(hA, batch, fw1, fb1, fw2, fb2, out,
                                           N_NODES, 712);
}